// Round 9
// baseline (186.681 us; speedup 1.0000x reference)
//
#include <hip/hip_runtime.h>
#include <hip/hip_bf16.h>

#define TAPS 901
#define CB 256
#define R 9                     // outputs/thread; odd -> conflict-free reads
#define NGRP 27                 // 27 groups of 9 taps, multiple of 3
#define NK (R * NGRP)           // 243 trimmed taps
#define OPB (CB * R)            // 2304 outputs per block
#define STAGE_E 2548            // staged floats (covers 255*9+8+243+1=2547)
#define TILE 2560               // lds floats (prefetch overreads < 2560)
#define WPAD 12                 // padded weight slots per group

__device__ __forceinline__ float4 ld4(const float* p) {
  return *reinterpret_cast<const float4*>(p);
}

// ---------------------------------------------------------------------------
// Kernel 1 (3 blocks): block 0 builds comb = conv(rot,gauss) trimmed to NK
// taps + bounds{clo4, flo, fhi}; blocks 1/2 recompute rot/gauss locally and
// do the exact two-stage conv for the lo/hi edge pixels (i<flo, i>=n-fhi),
// scattered into sums (conv_scatter skips those pixels).
// ---------------------------------------------------------------------------
__global__ __launch_bounds__(1024) void prep(
    const float* __restrict__ lns, const float* __restrict__ lnv,
    const float* __restrict__ flux, const int* __restrict__ ids,
    float* __restrict__ comb_w, int* __restrict__ bounds,
    float* __restrict__ sums, int n) {
  __shared__ float rk[1024], gk[1024], red[1024];
  __shared__ float ck[2048];            // block0: comb; blocks1/2: rbuf
  __shared__ int sb[8];                 // {rlo,rhi,glo,ghi,clo,chi}
  const int t = threadIdx.x;
  if (t < 8) sb[t] = (t & 1) ? -1 : 4096;
  __syncthreads();

  const float sigma = 0.01f + expf(lns[0]);
  const float vsini = 0.9f + expf(lnv[0]);

  float rv = 0.f, gv = 0.f;
  if (t < TAPS) {
    float g = -4.5f + 0.01f * (float)t;
    float x = (299792.458f * g / 10500.0f) / vsini;
    float x2 = fminf(x * x, 1.0f);
    if (x2 < 1.0f) rv = 2.0f * sqrtf(1.0f - x2);  // 0.99999999f rounds to 1.0f
    gv = (1.0f / (sigma * sqrtf(2.0f * 3.1415926654f))) *
         expf(-0.5f * g * g / (sigma * sigma)) * 0.01f;
  }
  red[t] = rv;
  __syncthreads();
  for (int s = 512; s > 0; s >>= 1) {
    if (t < s) red[t] += red[t + s];
    __syncthreads();
  }
  const float rsum = red[0];

  const float rw = (t < TAPS) ? rv / rsum : 0.f;
  rk[t] = rw;
  gk[t] = gv;
  if (t < TAPS) {
    if (rw != 0.f)          { atomicMin(&sb[0], t); atomicMax(&sb[1], t); }
    if (fabsf(gv) > 1e-10f) { atomicMin(&sb[2], t); atomicMax(&sb[3], t); }
  }
  __syncthreads();
  const int rlo = sb[0], rhi = sb[1], glo = sb[2], ghi = sb[3];
  int flo = 450 - glo; if (flo < 0) flo = 0;
  int fhi = ghi - 450; if (fhi < 0) fhi = 0;

  if (blockIdx.x == 0) {
    // combined kernel comb[t2] = sum_j rot[j]*gauss[t2-j], t2 in [0,1800]
    for (int t2 = t; t2 < 2048; t2 += 1024) {
      float c = 0.f;
      if (t2 <= 1800) {
        int jmin = rlo > t2 - ghi ? rlo : t2 - ghi;
        int jmax = rhi < t2 - glo ? rhi : t2 - glo;
        for (int j = jmin; j <= jmax; ++j) c += rk[j] * gk[t2 - j];
      }
      ck[t2] = c;
      comb_w[t2] = c;
      if (t2 <= 1800 && fabsf(c) > 1e-12f) { atomicMin(&sb[4], t2); atomicMax(&sb[5], t2); }
    }
    __syncthreads();
    if (t == 0) {
      int clo = sb[4], chi = sb[5];
      if (chi < clo) { clo = 900; chi = 900; }
      // trim smallest-|w| end taps until aligned window width fits NK
      while (chi - (clo & ~3) + 1 > NK) {
        if (fabsf(ck[clo]) <= fabsf(ck[chi])) ++clo; else --chi;
      }
      bounds[0] = clo & ~3; bounds[1] = flo; bounds[2] = fhi;
    }
  } else if (blockIdx.x == 1) {
    // lo edge: pixels i in [0, flo); r[j] for j in [0, m)
    const int m = flo + fhi;
    float* rbuf = ck;
    for (int j = t; j < m; j += 1024) {
      float s = 0.f;
      int j0 = 450 - j > rlo ? 450 - j : rlo;  // f index >= 0
      for (int j2 = j0; j2 <= rhi; ++j2) s += rk[j2] * flux[j + j2 - 450];
      rbuf[j] = s;
    }
    __syncthreads();
    for (int i = t; i < flo; i += 1024) {
      float c = 0.f;
      int k0 = 450 - i > glo ? 450 - i : glo;  // r index >= 0
      for (int k = k0; k <= ghi; ++k) c += gk[k] * rbuf[i + k - 450];
      atomicAdd(&sums[ids[i]], c);
    }
  } else {
    // hi edge: pixels i in [n-fhi, n); r[j] for j in [n-m, n)
    const int m = flo + fhi;
    float* rbuf = ck;
    const int jbase = n - m;
    for (int jj = t; jj < m; jj += 1024) {
      int j = jbase + jj;
      float s = 0.f;
      int j2hi = n - 1 + 450 - j < rhi ? n - 1 + 450 - j : rhi;  // f index < n
      for (int j2 = rlo; j2 <= j2hi; ++j2) s += rk[j2] * flux[j + j2 - 450];
      rbuf[jj] = s;
    }
    __syncthreads();
    for (int ii = t; ii < fhi; ii += 1024) {
      int i = n - fhi + ii;
      float c = 0.f;
      int khi = n - 1 + 450 - i < ghi ? n - 1 + 450 - i : ghi;  // r index < n
      for (int k = glo; k <= khi; ++k) c += gk[k] * rbuf[i + k - 450 - jbase];
      atomicAdd(&sums[ids[i]], c);
    }
  }
}

// ---------------------------------------------------------------------------
// Kernel 2: fused combined-conv + segment-sum scatter + bin-boundary scan.
// Inner loop: three-buffer register window (wA/wB/wC, period-3 role
// rotation, groups unrolled x3). Each group's 9 window ds_reads are issued a
// FULL group (162 FMA cycles) before first use -> LDS latency fully hidden
// (the R<=11 single-ring version had only ~1 tap of slack). Lane stride 9
// dwords (odd) -> 2 lanes/bank -> conflict-free (m136). Weights: LDS padded
// layout + 1-group register pipeline.
// ---------------------------------------------------------------------------
__global__ __launch_bounds__(CB, 4) void conv_scatter(
    const float* __restrict__ flux, const float* __restrict__ comb_w,
    const int* __restrict__ bounds, const int* __restrict__ ids,
    float* __restrict__ sums, int* __restrict__ bstart, int n, int nbins) {
  __shared__ __align__(16) float lds[TILE];
  __shared__ __align__(16) float wl[NGRP * WPAD];
  const int tid = threadIdx.x;
  const int clo4 = __builtin_amdgcn_readfirstlane(bounds[0]);
  const int flo  = __builtin_amdgcn_readfirstlane(bounds[1]);
  const int fhi  = __builtin_amdgcn_readfirstlane(bounds[2]);
  const int blockBase = blockIdx.x * OPB;
  const int start = blockBase - 900 + clo4;  // multiple of 4 -> float4-aligned

  // stage window: lds[j] = f_zeropad[start + j]
  if (start >= 0 && start + STAGE_E <= n) {
    for (int j = tid * 4; j < STAGE_E; j += CB * 4)
      *reinterpret_cast<float4*>(&lds[j]) = ld4(flux + start + j);
  } else {
    for (int j = tid * 4; j < STAGE_E; j += CB * 4) {
      int g = start + j;
      float4 v;
      v.x = (unsigned)g       < (unsigned)n ? flux[g]     : 0.f;
      v.y = (unsigned)(g + 1) < (unsigned)n ? flux[g + 1] : 0.f;
      v.z = (unsigned)(g + 2) < (unsigned)n ? flux[g + 2] : 0.f;
      v.w = (unsigned)(g + 3) < (unsigned)n ? flux[g + 3] : 0.f;
      *reinterpret_cast<float4*>(&lds[j]) = v;
    }
  }
  // weights, padded: slot g*12+u <-> tap g*9+u (u<9); u>=9 -> 0 pad
  for (int k = tid; k < NGRP * WPAD; k += CB) {
    const int g = k / WPAD, u = k % WPAD;
    wl[k] = (u < R) ? comb_w[clo4 + g * R + u] : 0.f;
  }
  __syncthreads();

  const int idx0 = tid * R;
  float wA[R], wB[R], wC[R];
#pragma unroll
  for (int i = 0; i < R; ++i) wA[i] = lds[idx0 + i];
#pragma unroll
  for (int i = 0; i < R; ++i) wB[i] = lds[idx0 + R + i];
  float acc[R];
#pragma unroll
  for (int r = 0; r < R; ++r) acc[r] = 0.f;

  const float4* wl4 = reinterpret_cast<const float4*>(wl);
  float4 wn0 = wl4[0], wn1 = wl4[1];
  float wn2 = wl[8];

  // weight scalar select (u is a literal after unrolling)
#define WSEL(u)                                                         \
  ((u) < 4 ? ((u) == 0 ? q0.x : (u) == 1 ? q0.y : (u) == 2 ? q0.z : q0.w) \
           : (u) < 8 ? ((u) == 4 ? q1.x : (u) == 5 ? q1.y : (u) == 6 ? q1.z : q1.w) \
                     : q2)
#define GRP(W0, W1, W2, GI)                                             \
  {                                                                     \
    const int kk = (GI) * R;                                            \
    _Pragma("unroll") for (int i = 0; i < R; ++i)                       \
        W2[i] = lds[idx0 + kk + 2 * R + i];   /* prefetch, used @GI+1 */ \
    const float4 q0 = wn0, q1 = wn1;                                    \
    const float q2 = wn2;                                               \
    const int gn = ((GI) + 1 < NGRP) ? (GI) + 1 : 0;                    \
    wn0 = wl4[gn * 3 + 0];                                              \
    wn1 = wl4[gn * 3 + 1];                                              \
    wn2 = wl[gn * WPAD + 8];                                            \
    _Pragma("unroll") for (int u = 0; u < R; ++u) {                     \
      const float wv = WSEL(u);                                         \
      _Pragma("unroll") for (int r = 0; r < R; ++r) {                   \
        const float val = (u + r < R) ? W0[u + r] : W1[u + r - R];      \
        acc[r] = fmaf(wv, val, acc[r]);                                 \
      }                                                                 \
    }                                                                   \
  }

  for (int m = 0; m < NGRP / 3; ++m) {
    GRP(wA, wB, wC, 3 * m)
    GRP(wB, wC, wA, 3 * m + 1)
    GRP(wC, wA, wB, 3 * m + 2)
  }
#undef GRP
#undef WSEL

  // epilogue: run-merged scatter (skip edge pixels handled by prep) +
  // bin-start boundary writes for ALL owned pixels.
  const int base = blockBase + idx0;
  const int loskip = flo - base;        // r < loskip: edge-handled
  const int hicap = (n - fhi) - base;   // r >= hicap: edge-handled
  int prev = (base > 0) ? ((base < n) ? ids[base - 1] : 0) : -1;
  int cur = -1; float run = 0.f;
#pragma unroll
  for (int r = 0; r < R; ++r) {
    const int p = base + r;
    if (p < n) {
      const int id = ids[p];
      if (id != prev) {
        for (int b = prev + 1; b <= id; ++b) bstart[b] = p;
        prev = id;
      }
      if (r >= loskip && r < hicap) {
        if (id == cur) {
          run += acc[r];
        } else {
          if (cur >= 0) atomicAdd(&sums[cur], run);
          cur = id; run = acc[r];
        }
      }
    }
  }
  if (cur >= 0) atomicAdd(&sums[cur], run);
  // tail fill: thread owning pixel n-1 covers bins after the last id
  if (base < n && base + R > n - 1) {
    for (int b = prev + 1; b < nbins; ++b) bstart[b] = n;
  }
}

// ---------------------------------------------------------------------------
// Kernel 3: per-bin mean from precomputed bin starts (coalesced, no search).
// ---------------------------------------------------------------------------
__global__ __launch_bounds__(256) void seg_mean(
    const float* __restrict__ sums, const int* __restrict__ bstart,
    float* __restrict__ out, int out_n) {
  const int gid = blockIdx.x * blockDim.x + threadIdx.x;
  if (gid >= out_n) return;
  const int b = gid + 1;
  const int c = bstart[b + 1] - bstart[b];
  const float mean = sums[b] / (float)(c > 1 ? c : 1);
  out[gid] = fminf(fmaxf(mean, 0.f), 1.f);
}

// ---------------------------------------------------------------------------
extern "C" void kernel_launch(void* const* d_in, const int* in_sizes, int n_in,
                              void* d_out, int out_size, void* d_ws,
                              size_t ws_size, hipStream_t stream) {
  const float* flux = (const float*)d_in[0];
  const float* lns  = (const float*)d_in[1];
  const float* lnv  = (const float*)d_in[2];
  const int*   ids  = (const int*)d_in[3];
  float* out = (float*)d_out;
  const int n = in_sizes[0];
  const int nbins = out_size + 2;

  // ws layout (floats): comb_w[2048] | bounds(int)[64] | sums[nbins] |
  //                     bstart(int)[nbins+1]
  float* ws      = (float*)d_ws;
  float* comb_w  = ws;
  int*   bounds  = (int*)(ws + 2048);
  float* sums    = ws + 2112;
  int*   bstart  = (int*)(sums + nbins);

  hipMemsetAsync(sums, 0, (size_t)nbins * sizeof(float), stream);
  prep<<<3, 1024, 0, stream>>>(lns, lnv, flux, ids, comb_w, bounds, sums, n);
  const int nblk = (n + OPB - 1) / OPB;
  conv_scatter<<<nblk, CB, 0, stream>>>(flux, comb_w, bounds, ids, sums,
                                        bstart, n, nbins);
  seg_mean<<<(out_size + 255) / 256, 256, 0, stream>>>(sums, bstart, out,
                                                       out_size);
}

// Round 10
// 153.715 us; speedup vs baseline: 1.2145x; 1.2145x over previous
//
#include <hip/hip_runtime.h>
#include <hip/hip_bf16.h>

#define TAPS 901
#define CB 256
#define R 9                     // outputs/thread; odd -> conflict-free reads
#define NGRP 27                 // 27 groups of 9 taps, multiple of 3
#define NK (R * NGRP)           // 243 trimmed taps
#define OPB (CB * R)            // 2304 outputs per block
#define STAGE_E 2548            // staged floats (covers 255*9+8+243+1=2547)
#define TILE 2560               // lds floats (prefetch overreads < 2560)
#define WPAD 12                 // padded weight slots per group

__device__ __forceinline__ float4 ld4(const float* p) {
  return *reinterpret_cast<const float4*>(p);
}

// ---------------------------------------------------------------------------
// Kernel 1 (3 blocks): block 0 builds comb = conv(rot,gauss) trimmed to NK
// taps + bounds{clo4, flo, fhi}; blocks 1/2 recompute rot/gauss locally and
// do the exact two-stage conv for the lo/hi edge pixels (i<flo, i>=n-fhi),
// scattered into sums (conv_scatter skips those pixels).
// ---------------------------------------------------------------------------
__global__ __launch_bounds__(1024) void prep(
    const float* __restrict__ lns, const float* __restrict__ lnv,
    const float* __restrict__ flux, const int* __restrict__ ids,
    float* __restrict__ comb_w, int* __restrict__ bounds,
    float* __restrict__ sums, int n) {
  __shared__ float rk[1024], gk[1024], red[1024];
  __shared__ float ck[2048];            // block0: comb; blocks1/2: rbuf
  __shared__ int sb[8];                 // {rlo,rhi,glo,ghi,clo,chi}
  const int t = threadIdx.x;
  if (t < 8) sb[t] = (t & 1) ? -1 : 4096;
  __syncthreads();

  const float sigma = 0.01f + expf(lns[0]);
  const float vsini = 0.9f + expf(lnv[0]);

  float rv = 0.f, gv = 0.f;
  if (t < TAPS) {
    float g = -4.5f + 0.01f * (float)t;
    float x = (299792.458f * g / 10500.0f) / vsini;
    float x2 = fminf(x * x, 1.0f);
    if (x2 < 1.0f) rv = 2.0f * sqrtf(1.0f - x2);  // 0.99999999f rounds to 1.0f
    gv = (1.0f / (sigma * sqrtf(2.0f * 3.1415926654f))) *
         expf(-0.5f * g * g / (sigma * sigma)) * 0.01f;
  }
  red[t] = rv;
  __syncthreads();
  for (int s = 512; s > 0; s >>= 1) {
    if (t < s) red[t] += red[t + s];
    __syncthreads();
  }
  const float rsum = red[0];

  const float rw = (t < TAPS) ? rv / rsum : 0.f;
  rk[t] = rw;
  gk[t] = gv;
  if (t < TAPS) {
    if (rw != 0.f)          { atomicMin(&sb[0], t); atomicMax(&sb[1], t); }
    if (fabsf(gv) > 1e-10f) { atomicMin(&sb[2], t); atomicMax(&sb[3], t); }
  }
  __syncthreads();
  const int rlo = sb[0], rhi = sb[1], glo = sb[2], ghi = sb[3];
  int flo = 450 - glo; if (flo < 0) flo = 0;
  int fhi = ghi - 450; if (fhi < 0) fhi = 0;

  if (blockIdx.x == 0) {
    // combined kernel comb[t2] = sum_j rot[j]*gauss[t2-j], t2 in [0,1800]
    for (int t2 = t; t2 < 2048; t2 += 1024) {
      float c = 0.f;
      if (t2 <= 1800) {
        int jmin = rlo > t2 - ghi ? rlo : t2 - ghi;
        int jmax = rhi < t2 - glo ? rhi : t2 - glo;
        for (int j = jmin; j <= jmax; ++j) c += rk[j] * gk[t2 - j];
      }
      ck[t2] = c;
      comb_w[t2] = c;
      if (t2 <= 1800 && fabsf(c) > 1e-12f) { atomicMin(&sb[4], t2); atomicMax(&sb[5], t2); }
    }
    __syncthreads();
    if (t == 0) {
      int clo = sb[4], chi = sb[5];
      if (chi < clo) { clo = 900; chi = 900; }
      // trim smallest-|w| end taps until aligned window width fits NK
      while (chi - (clo & ~3) + 1 > NK) {
        if (fabsf(ck[clo]) <= fabsf(ck[chi])) ++clo; else --chi;
      }
      bounds[0] = clo & ~3; bounds[1] = flo; bounds[2] = fhi;
    }
  } else if (blockIdx.x == 1) {
    // lo edge: pixels i in [0, flo); r[j] for j in [0, m)
    const int m = flo + fhi;
    float* rbuf = ck;
    for (int j = t; j < m; j += 1024) {
      float s = 0.f;
      int j0 = 450 - j > rlo ? 450 - j : rlo;  // f index >= 0
      for (int j2 = j0; j2 <= rhi; ++j2) s += rk[j2] * flux[j + j2 - 450];
      rbuf[j] = s;
    }
    __syncthreads();
    for (int i = t; i < flo; i += 1024) {
      float c = 0.f;
      int k0 = 450 - i > glo ? 450 - i : glo;  // r index >= 0
      for (int k = k0; k <= ghi; ++k) c += gk[k] * rbuf[i + k - 450];
      atomicAdd(&sums[ids[i]], c);
    }
  } else {
    // hi edge: pixels i in [n-fhi, n); r[j] for j in [n-m, n)
    const int m = flo + fhi;
    float* rbuf = ck;
    const int jbase = n - m;
    for (int jj = t; jj < m; jj += 1024) {
      int j = jbase + jj;
      float s = 0.f;
      int j2hi = n - 1 + 450 - j < rhi ? n - 1 + 450 - j : rhi;  // f index < n
      for (int j2 = rlo; j2 <= j2hi; ++j2) s += rk[j2] * flux[j + j2 - 450];
      rbuf[jj] = s;
    }
    __syncthreads();
    for (int ii = t; ii < fhi; ii += 1024) {
      int i = n - fhi + ii;
      float c = 0.f;
      int khi = n - 1 + 450 - i < ghi ? n - 1 + 450 - i : ghi;  // r index < n
      for (int k = glo; k <= khi; ++k) c += gk[k] * rbuf[i + k - 450 - jbase];
      atomicAdd(&sums[ids[i]], c);
    }
  }
}

// ---------------------------------------------------------------------------
// Kernel 2: fused combined-conv + segment-sum scatter + bin-boundary scan.
// Inner loop: three-buffer register window (wA/wB/wC, period-3 role
// rotation, groups unrolled x3). Each group's 9 window ds_reads are issued a
// FULL group (162 FMA cycles) before first use -> LDS latency fully hidden.
// Lane stride 9 dwords (odd) -> 2 lanes/bank -> conflict-free (m136).
// NOTE: no min-waves in launch_bounds — R9's (CB,4) capped VGPR at 64 and
// spilled ~50 floats/thread to scratch (FETCH 98MB, WRITE 93MB, 89µs).
// ---------------------------------------------------------------------------
__global__ __launch_bounds__(CB) void conv_scatter(
    const float* __restrict__ flux, const float* __restrict__ comb_w,
    const int* __restrict__ bounds, const int* __restrict__ ids,
    float* __restrict__ sums, int* __restrict__ bstart, int n, int nbins) {
  __shared__ __align__(16) float lds[TILE];
  __shared__ __align__(16) float wl[NGRP * WPAD];
  const int tid = threadIdx.x;
  const int clo4 = __builtin_amdgcn_readfirstlane(bounds[0]);
  const int flo  = __builtin_amdgcn_readfirstlane(bounds[1]);
  const int fhi  = __builtin_amdgcn_readfirstlane(bounds[2]);
  const int blockBase = blockIdx.x * OPB;
  const int start = blockBase - 900 + clo4;  // multiple of 4 -> float4-aligned

  // stage window: lds[j] = f_zeropad[start + j]
  if (start >= 0 && start + STAGE_E <= n) {
    for (int j = tid * 4; j < STAGE_E; j += CB * 4)
      *reinterpret_cast<float4*>(&lds[j]) = ld4(flux + start + j);
  } else {
    for (int j = tid * 4; j < STAGE_E; j += CB * 4) {
      int g = start + j;
      float4 v;
      v.x = (unsigned)g       < (unsigned)n ? flux[g]     : 0.f;
      v.y = (unsigned)(g + 1) < (unsigned)n ? flux[g + 1] : 0.f;
      v.z = (unsigned)(g + 2) < (unsigned)n ? flux[g + 2] : 0.f;
      v.w = (unsigned)(g + 3) < (unsigned)n ? flux[g + 3] : 0.f;
      *reinterpret_cast<float4*>(&lds[j]) = v;
    }
  }
  // weights, padded: slot g*12+u <-> tap g*9+u (u<9); u>=9 -> 0 pad
  for (int k = tid; k < NGRP * WPAD; k += CB) {
    const int g = k / WPAD, u = k % WPAD;
    wl[k] = (u < R) ? comb_w[clo4 + g * R + u] : 0.f;
  }
  __syncthreads();

  const int idx0 = tid * R;
  float wA[R], wB[R], wC[R];
#pragma unroll
  for (int i = 0; i < R; ++i) wA[i] = lds[idx0 + i];
#pragma unroll
  for (int i = 0; i < R; ++i) wB[i] = lds[idx0 + R + i];
  float acc[R];
#pragma unroll
  for (int r = 0; r < R; ++r) acc[r] = 0.f;

  const float4* wl4 = reinterpret_cast<const float4*>(wl);
  float4 wn0 = wl4[0], wn1 = wl4[1];
  float wn2 = wl[8];

  // weight scalar select (u is a literal after unrolling)
#define WSEL(u)                                                         \
  ((u) < 4 ? ((u) == 0 ? q0.x : (u) == 1 ? q0.y : (u) == 2 ? q0.z : q0.w) \
           : (u) < 8 ? ((u) == 4 ? q1.x : (u) == 5 ? q1.y : (u) == 6 ? q1.z : q1.w) \
                     : q2)
#define GRP(W0, W1, W2, GI)                                             \
  {                                                                     \
    const int kk = (GI) * R;                                            \
    _Pragma("unroll") for (int i = 0; i < R; ++i)                       \
        W2[i] = lds[idx0 + kk + 2 * R + i];   /* prefetch, used @GI+1 */ \
    const float4 q0 = wn0, q1 = wn1;                                    \
    const float q2 = wn2;                                               \
    const int gn = ((GI) + 1 < NGRP) ? (GI) + 1 : 0;                    \
    wn0 = wl4[gn * 3 + 0];                                              \
    wn1 = wl4[gn * 3 + 1];                                              \
    wn2 = wl[gn * WPAD + 8];                                            \
    _Pragma("unroll") for (int u = 0; u < R; ++u) {                     \
      const float wv = WSEL(u);                                         \
      _Pragma("unroll") for (int r = 0; r < R; ++r) {                   \
        const float val = (u + r < R) ? W0[u + r] : W1[u + r - R];      \
        acc[r] = fmaf(wv, val, acc[r]);                                 \
      }                                                                 \
    }                                                                   \
  }

  for (int m = 0; m < NGRP / 3; ++m) {
    GRP(wA, wB, wC, 3 * m)
    GRP(wB, wC, wA, 3 * m + 1)
    GRP(wC, wA, wB, 3 * m + 2)
  }
#undef GRP
#undef WSEL

  // epilogue: run-merged scatter (skip edge pixels handled by prep) +
  // bin-start boundary writes for ALL owned pixels.
  const int base = blockBase + idx0;
  const int loskip = flo - base;        // r < loskip: edge-handled
  const int hicap = (n - fhi) - base;   // r >= hicap: edge-handled
  int prev = (base > 0) ? ((base < n) ? ids[base - 1] : 0) : -1;
  int cur = -1; float run = 0.f;
#pragma unroll
  for (int r = 0; r < R; ++r) {
    const int p = base + r;
    if (p < n) {
      const int id = ids[p];
      if (id != prev) {
        for (int b = prev + 1; b <= id; ++b) bstart[b] = p;
        prev = id;
      }
      if (r >= loskip && r < hicap) {
        if (id == cur) {
          run += acc[r];
        } else {
          if (cur >= 0) atomicAdd(&sums[cur], run);
          cur = id; run = acc[r];
        }
      }
    }
  }
  if (cur >= 0) atomicAdd(&sums[cur], run);
  // tail fill: thread owning pixel n-1 covers bins after the last id
  if (base < n && base + R > n - 1) {
    for (int b = prev + 1; b < nbins; ++b) bstart[b] = n;
  }
}

// ---------------------------------------------------------------------------
// Kernel 3: per-bin mean from precomputed bin starts (coalesced, no search).
// ---------------------------------------------------------------------------
__global__ __launch_bounds__(256) void seg_mean(
    const float* __restrict__ sums, const int* __restrict__ bstart,
    float* __restrict__ out, int out_n) {
  const int gid = blockIdx.x * blockDim.x + threadIdx.x;
  if (gid >= out_n) return;
  const int b = gid + 1;
  const int c = bstart[b + 1] - bstart[b];
  const float mean = sums[b] / (float)(c > 1 ? c : 1);
  out[gid] = fminf(fmaxf(mean, 0.f), 1.f);
}

// ---------------------------------------------------------------------------
extern "C" void kernel_launch(void* const* d_in, const int* in_sizes, int n_in,
                              void* d_out, int out_size, void* d_ws,
                              size_t ws_size, hipStream_t stream) {
  const float* flux = (const float*)d_in[0];
  const float* lns  = (const float*)d_in[1];
  const float* lnv  = (const float*)d_in[2];
  const int*   ids  = (const int*)d_in[3];
  float* out = (float*)d_out;
  const int n = in_sizes[0];
  const int nbins = out_size + 2;

  // ws layout (floats): comb_w[2048] | bounds(int)[64] | sums[nbins] |
  //                     bstart(int)[nbins+1]
  float* ws      = (float*)d_ws;
  float* comb_w  = ws;
  int*   bounds  = (int*)(ws + 2048);
  float* sums    = ws + 2112;
  int*   bstart  = (int*)(sums + nbins);

  hipMemsetAsync(sums, 0, (size_t)nbins * sizeof(float), stream);
  prep<<<3, 1024, 0, stream>>>(lns, lnv, flux, ids, comb_w, bounds, sums, n);
  const int nblk = (n + OPB - 1) / OPB;
  conv_scatter<<<nblk, CB, 0, stream>>>(flux, comb_w, bounds, ids, sums,
                                        bstart, n, nbins);
  seg_mean<<<(out_size + 255) / 256, 256, 0, stream>>>(sums, bstart, out,
                                                       out_size);
}

// Round 11
// 141.522 us; speedup vs baseline: 1.3191x; 1.0862x over previous
//
#include <hip/hip_runtime.h>
#include <hip/hip_bf16.h>

#define TAPS 901
#define CB 128                  // smaller blocks -> 2185 blocks = 8.5/CU (TLP)
#define R 15                    // outputs/thread; odd -> conflict-free reads
#define NGRP 16
#define NK (R * NGRP)           // 240 trimmed taps
#define OPB (CB * R)            // 1920 outputs per block
#define STAGE_N 2160            // staged floats (127*15+14+240+1 = 2160)
#define TILE 2176
#define WPAD 16                 // padded weight slots per group (4 float4)

__device__ __forceinline__ float4 ld4(const float* p) {
  return *reinterpret_cast<const float4*>(p);
}

// ---------------------------------------------------------------------------
// Kernel 1 (3 blocks): block 0 builds comb = conv(rot,gauss) trimmed to NK
// taps + bounds{clo4, flo, fhi}; blocks 1/2 recompute rot/gauss locally and
// do the exact two-stage conv for the lo/hi edge pixels (i<flo, i>=n-fhi),
// scattered into sums (conv_scatter skips those pixels).
// ---------------------------------------------------------------------------
__global__ __launch_bounds__(1024) void prep(
    const float* __restrict__ lns, const float* __restrict__ lnv,
    const float* __restrict__ flux, const int* __restrict__ ids,
    float* __restrict__ comb_w, int* __restrict__ bounds,
    float* __restrict__ sums, int n) {
  __shared__ float rk[1024], gk[1024], red[1024];
  __shared__ float ck[2048];            // block0: comb; blocks1/2: rbuf
  __shared__ int sb[8];                 // {rlo,rhi,glo,ghi,clo,chi}
  const int t = threadIdx.x;
  if (t < 8) sb[t] = (t & 1) ? -1 : 4096;
  __syncthreads();

  const float sigma = 0.01f + expf(lns[0]);
  const float vsini = 0.9f + expf(lnv[0]);

  float rv = 0.f, gv = 0.f;
  if (t < TAPS) {
    float g = -4.5f + 0.01f * (float)t;
    float x = (299792.458f * g / 10500.0f) / vsini;
    float x2 = fminf(x * x, 1.0f);
    if (x2 < 1.0f) rv = 2.0f * sqrtf(1.0f - x2);  // 0.99999999f rounds to 1.0f
    gv = (1.0f / (sigma * sqrtf(2.0f * 3.1415926654f))) *
         expf(-0.5f * g * g / (sigma * sigma)) * 0.01f;
  }
  red[t] = rv;
  __syncthreads();
  for (int s = 512; s > 0; s >>= 1) {
    if (t < s) red[t] += red[t + s];
    __syncthreads();
  }
  const float rsum = red[0];

  const float rw = (t < TAPS) ? rv / rsum : 0.f;
  rk[t] = rw;
  gk[t] = gv;
  if (t < TAPS) {
    if (rw != 0.f)          { atomicMin(&sb[0], t); atomicMax(&sb[1], t); }
    if (fabsf(gv) > 1e-10f) { atomicMin(&sb[2], t); atomicMax(&sb[3], t); }
  }
  __syncthreads();
  const int rlo = sb[0], rhi = sb[1], glo = sb[2], ghi = sb[3];
  int flo = 450 - glo; if (flo < 0) flo = 0;
  int fhi = ghi - 450; if (fhi < 0) fhi = 0;

  if (blockIdx.x == 0) {
    // combined kernel comb[t2] = sum_j rot[j]*gauss[t2-j], t2 in [0,1800]
    for (int t2 = t; t2 < 2048; t2 += 1024) {
      float c = 0.f;
      if (t2 <= 1800) {
        int jmin = rlo > t2 - ghi ? rlo : t2 - ghi;
        int jmax = rhi < t2 - glo ? rhi : t2 - glo;
        for (int j = jmin; j <= jmax; ++j) c += rk[j] * gk[t2 - j];
      }
      ck[t2] = c;
      comb_w[t2] = c;
      if (t2 <= 1800 && fabsf(c) > 1e-12f) { atomicMin(&sb[4], t2); atomicMax(&sb[5], t2); }
    }
    __syncthreads();
    if (t == 0) {
      int clo = sb[4], chi = sb[5];
      if (chi < clo) { clo = 900; chi = 900; }
      // trim smallest-|w| end taps until aligned window width fits NK
      while (chi - (clo & ~3) + 1 > NK) {
        if (fabsf(ck[clo]) <= fabsf(ck[chi])) ++clo; else --chi;
      }
      bounds[0] = clo & ~3; bounds[1] = flo; bounds[2] = fhi;
    }
  } else if (blockIdx.x == 1) {
    // lo edge: pixels i in [0, flo); r[j] for j in [0, m)
    const int m = flo + fhi;
    float* rbuf = ck;
    for (int j = t; j < m; j += 1024) {
      float s = 0.f;
      int j0 = 450 - j > rlo ? 450 - j : rlo;  // f index >= 0
      for (int j2 = j0; j2 <= rhi; ++j2) s += rk[j2] * flux[j + j2 - 450];
      rbuf[j] = s;
    }
    __syncthreads();
    for (int i = t; i < flo; i += 1024) {
      float c = 0.f;
      int k0 = 450 - i > glo ? 450 - i : glo;  // r index >= 0
      for (int k = k0; k <= ghi; ++k) c += gk[k] * rbuf[i + k - 450];
      atomicAdd(&sums[ids[i]], c);
    }
  } else {
    // hi edge: pixels i in [n-fhi, n); r[j] for j in [n-m, n)
    const int m = flo + fhi;
    float* rbuf = ck;
    const int jbase = n - m;
    for (int jj = t; jj < m; jj += 1024) {
      int j = jbase + jj;
      float s = 0.f;
      int j2hi = n - 1 + 450 - j < rhi ? n - 1 + 450 - j : rhi;  // f index < n
      for (int j2 = rlo; j2 <= j2hi; ++j2) s += rk[j2] * flux[j + j2 - 450];
      rbuf[jj] = s;
    }
    __syncthreads();
    for (int ii = t; ii < fhi; ii += 1024) {
      int i = n - fhi + ii;
      float c = 0.f;
      int khi = n - 1 + 450 - i < ghi ? n - 1 + 450 - i : ghi;  // r index < n
      for (int k = glo; k <= khi; ++k) c += gk[k] * rbuf[i + k - 450 - jbase];
      atomicAdd(&sums[ids[i]], c);
    }
  }
}

// ---------------------------------------------------------------------------
// Kernel 2: fused combined-conv + segment-sum scatter + bin-boundary scan.
// Low-VGPR single-ring window (R=15, lane stride 15 dwords -> conflict-free,
// m136) + 1-group weight register pipeline. CB=128 so the whole grid
// (2185 blocks, 8.5/CU) is co-resident: TLP, not ILP, is the lever (R10's
// high-VGPR 3-buffer pipeline halved occupancy and lost 45%).
// ---------------------------------------------------------------------------
__global__ __launch_bounds__(CB) void conv_scatter(
    const float* __restrict__ flux, const float* __restrict__ comb_w,
    const int* __restrict__ bounds, const int* __restrict__ ids,
    float* __restrict__ sums, int* __restrict__ bstart, int n, int nbins) {
  __shared__ __align__(16) float lds[TILE];
  __shared__ __align__(16) float wl[NGRP * WPAD];
  const int tid = threadIdx.x;
  const int clo4 = __builtin_amdgcn_readfirstlane(bounds[0]);
  const int flo  = __builtin_amdgcn_readfirstlane(bounds[1]);
  const int fhi  = __builtin_amdgcn_readfirstlane(bounds[2]);
  const int blockBase = blockIdx.x * OPB;
  const int start = blockBase - 900 + clo4;  // multiple of 4 -> float4-aligned

  // stage window: lds[j] = f_zeropad[start + j]
  if (start >= 0 && start + STAGE_N <= n) {
    for (int j = tid * 4; j < STAGE_N; j += CB * 4)
      *reinterpret_cast<float4*>(&lds[j]) = ld4(flux + start + j);
  } else {
    for (int j = tid * 4; j < STAGE_N; j += CB * 4) {
      int g = start + j;
      float4 v;
      v.x = (unsigned)g       < (unsigned)n ? flux[g]     : 0.f;
      v.y = (unsigned)(g + 1) < (unsigned)n ? flux[g + 1] : 0.f;
      v.z = (unsigned)(g + 2) < (unsigned)n ? flux[g + 2] : 0.f;
      v.w = (unsigned)(g + 3) < (unsigned)n ? flux[g + 3] : 0.f;
      *reinterpret_cast<float4*>(&lds[j]) = v;
    }
  }
  // weights, padded: slot g*16+u <-> tap g*15+u (u<15); u==15 -> 0 pad
  for (int k = tid; k < NGRP * WPAD; k += CB) {
    const int g = k >> 4, u = k & 15;
    wl[k] = (u < R) ? comb_w[clo4 + g * R + u] : 0.f;
  }
  __syncthreads();

  const int idx0 = tid * R;
  float win[R];
#pragma unroll
  for (int r = 0; r < R; ++r) win[r] = lds[idx0 + r];
  float acc[R];
#pragma unroll
  for (int r = 0; r < R; ++r) acc[r] = 0.f;

  const float4* wl4 = reinterpret_cast<const float4*>(wl);
  float4 n0 = wl4[0], n1 = wl4[1], n2 = wl4[2], n3 = wl4[3];

#define TAP(u, wv)                                                     \
  {                                                                    \
    _Pragma("unroll") for (int r = 0; r < R; ++r)                      \
        acc[r] = fmaf(wv, win[((u) + r) % R], acc[r]);                 \
    win[u] = lds[idx0 + kk + (u) + R];                                 \
  }
#pragma unroll 2
  for (int g = 0; g < NGRP; ++g) {
    const int kk = g * R;
    const float4 q0 = n0, q1 = n1, q2 = n2, q3 = n3;
    if (g + 1 < NGRP) {
      n0 = wl4[(g + 1) * 4 + 0];
      n1 = wl4[(g + 1) * 4 + 1];
      n2 = wl4[(g + 1) * 4 + 2];
      n3 = wl4[(g + 1) * 4 + 3];
    }
    TAP(0, q0.x)  TAP(1, q0.y)  TAP(2, q0.z)  TAP(3, q0.w)
    TAP(4, q1.x)  TAP(5, q1.y)  TAP(6, q1.z)  TAP(7, q1.w)
    TAP(8, q2.x)  TAP(9, q2.y)  TAP(10, q2.z) TAP(11, q2.w)
    TAP(12, q3.x) TAP(13, q3.y) TAP(14, q3.z)       // q3.w is pad
  }
#undef TAP

  // epilogue: run-merged scatter (skip edge pixels handled by prep) +
  // bin-start boundary writes for ALL owned pixels.
  const int base = blockBase + idx0;
  const int loskip = flo - base;        // r < loskip: edge-handled
  const int hicap = (n - fhi) - base;   // r >= hicap: edge-handled
  int prev = (base > 0) ? ((base < n) ? ids[base - 1] : 0) : -1;
  int cur = -1; float run = 0.f;
#pragma unroll
  for (int r = 0; r < R; ++r) {
    const int p = base + r;
    if (p < n) {
      const int id = ids[p];
      if (id != prev) {
        for (int b = prev + 1; b <= id; ++b) bstart[b] = p;
        prev = id;
      }
      if (r >= loskip && r < hicap) {
        if (id == cur) {
          run += acc[r];
        } else {
          if (cur >= 0) atomicAdd(&sums[cur], run);
          cur = id; run = acc[r];
        }
      }
    }
  }
  if (cur >= 0) atomicAdd(&sums[cur], run);
  // tail fill: thread owning pixel n-1 covers bins after the last id
  if (base < n && base + R > n - 1) {
    for (int b = prev + 1; b < nbins; ++b) bstart[b] = n;
  }
}

// ---------------------------------------------------------------------------
// Kernel 3: per-bin mean from precomputed bin starts (coalesced, no search).
// ---------------------------------------------------------------------------
__global__ __launch_bounds__(256) void seg_mean(
    const float* __restrict__ sums, const int* __restrict__ bstart,
    float* __restrict__ out, int out_n) {
  const int gid = blockIdx.x * blockDim.x + threadIdx.x;
  if (gid >= out_n) return;
  const int b = gid + 1;
  const int c = bstart[b + 1] - bstart[b];
  const float mean = sums[b] / (float)(c > 1 ? c : 1);
  out[gid] = fminf(fmaxf(mean, 0.f), 1.f);
}

// ---------------------------------------------------------------------------
extern "C" void kernel_launch(void* const* d_in, const int* in_sizes, int n_in,
                              void* d_out, int out_size, void* d_ws,
                              size_t ws_size, hipStream_t stream) {
  const float* flux = (const float*)d_in[0];
  const float* lns  = (const float*)d_in[1];
  const float* lnv  = (const float*)d_in[2];
  const int*   ids  = (const int*)d_in[3];
  float* out = (float*)d_out;
  const int n = in_sizes[0];
  const int nbins = out_size + 2;

  // ws layout (floats): comb_w[2048] | bounds(int)[64] | sums[nbins] |
  //                     bstart(int)[nbins+1]
  float* ws      = (float*)d_ws;
  float* comb_w  = ws;
  int*   bounds  = (int*)(ws + 2048);
  float* sums    = ws + 2112;
  int*   bstart  = (int*)(sums + nbins);

  hipMemsetAsync(sums, 0, (size_t)nbins * sizeof(float), stream);
  prep<<<3, 1024, 0, stream>>>(lns, lnv, flux, ids, comb_w, bounds, sums, n);
  const int nblk = (n + OPB - 1) / OPB;
  conv_scatter<<<nblk, CB, 0, stream>>>(flux, comb_w, bounds, ids, sums,
                                        bstart, n, nbins);
  seg_mean<<<(out_size + 255) / 256, 256, 0, stream>>>(sums, bstart, out,
                                                       out_size);
}